// Round 3
// baseline (357.341 us; speedup 1.0000x reference)
//
#include <hip/hip_runtime.h>
#include <math.h>

typedef __bf16 bf16x8 __attribute__((ext_vector_type(8)));
typedef float f32x4 __attribute__((ext_vector_type(4)));
typedef unsigned short u16;

#define NB 8  // batch elements per block; grid = 16384/NB

__device__ __forceinline__ u16 f2b(float f) {
  // fp32 -> bf16 round-to-nearest-even (finite inputs only)
  unsigned u = __builtin_bit_cast(unsigned, f);
  u = (u + 0x7fffu + ((u >> 16) & 1u)) >> 16;
  return (u16)u;
}

__device__ __forceinline__ f32x4 mfma16(bf16x8 a, bf16x8 b, f32x4 c) {
  return __builtin_amdgcn_mfma_f32_16x16x32_bf16(a, b, c, 0, 0, 0);
}

// XOR-swizzled LDS addressing: tiles are [rows][64 u16], 16B chunk index XORed
// with (row & 7). Every b128 access stays 16B-aligned AND bank-conflict-free
// for row-fragment reads and column-ish scatter writes.
__device__ __forceinline__ int sw(int r, int c) {      // element (u16) address
  return (r << 6) + ((((c >> 3) ^ r) & 7) << 3) + (c & 7);
}
__device__ __forceinline__ int swc(int r, int ch) {    // chunk (16B) address
  return (r << 6) + (((ch ^ r) & 7) << 3);
}

// Prep: bf16 weight image in ws (pre-swizzled, rows of 64 u16):
//   rows 0-47:  M_t[c'][c] = scale * sum_h Wq[c][h]*Wk[c'][h]  ((scale*Wq@Wk^T)^T)
//   rows 48-95: Wv_t[h][c] = Wv[c][h]
// cols 48-63 zeroed (K-dim pad). LDS-staged (round-1 scalar-global version was
// single-block latency-bound).
__global__ __launch_bounds__(256) void head_prep(const float* __restrict__ Wq,
                                                 const float* __restrict__ Wk,
                                                 const float* __restrict__ Wv,
                                                 u16* __restrict__ ws) {
  __shared__ float wq[2304], wk[2304], wv[2304];
  const float scale = 0.14433756729740643f;  // 1/sqrt(48)
  for (int i = threadIdx.x; i < 2304; i += 256) {
    wq[i] = Wq[i];
    wk[i] = Wk[i];
    wv[i] = Wv[i];
  }
  __syncthreads();
  for (int idx = threadIdx.x; idx < 96 * 64; idx += 256) {
    int r = idx >> 6, c = idx & 63;
    float v = 0.f;
    if (c < 48) {
      if (r < 48) {
        float a = 0.f;
        for (int h = 0; h < 48; ++h) a += wq[c * 48 + h] * wk[r * 48 + h];
        v = a * scale;
      } else {
        v = wv[c * 48 + (r - 48)];
      }
    }
    ws[sw(r, c)] = f2b(v);
  }
}

// One workgroup (4 waves) handles NB batch elements sequentially; wave w owns
// t-rows [16w,16w+16) of each. Software pipeline: x_{i+1} is prefetched into
// registers at the top of iteration i, hiding HBM latency behind compute.
// qm = x@M ; S = qm@x^T (== scale*q@k^T) ; P = softmax_causal(S) ; out = P@(x@Wv)
// LDS (34816 B -> 4 blocks/CU, 16 waves):
//   W  rows 0-95   : M (0-47) | Wv_t (48-95)      — staged once per block
//   QM rows 96-159 : q@M, per-wave private rows (write->read needs only a fence)
//   X  rows 160-223: x bf16; overlaid by P after the S phase each iteration
//   VT rows 224-271: V transposed (h-major, s-inner), rewritten each iteration
__global__ __launch_bounds__(256, 4) void head_main(const float* __restrict__ x,
                                                    const u16* __restrict__ wimg,
                                                    float* __restrict__ out) {
  __shared__ u16 lds[272 * 64];
  u16* const W  = lds;
  u16* const QM = lds + 96 * 64;
  u16* const X  = lds + 160 * 64;
  u16* const VT = lds + 224 * 64;

  const int tid  = threadIdx.x;
  const int lane = tid & 63;
  const int w    = tid >> 6;
  const int qd   = lane >> 4;
  const int col  = lane & 15;
  const long b0  = (long)blockIdx.x * NB;

  // ---- stage weight image once (768 uint4 from L2) ----
  {
    const uint4* src = (const uint4*)wimg;
    uint4* dst = (uint4*)lds;
    dst[tid]       = src[tid];
    dst[tid + 256] = src[tid + 256];
    dst[tid + 512] = src[tid + 512];
  }
  // ---- zero QM K-pad once (chunks 6,7 of 64 rows; pad survives all iters) ----
  {
    ushort4 z = {0, 0, 0, 0};
    int zr = tid >> 2, zq = tid & 3;
    *(ushort4*)(QM + swc(zr, 6 + (zq >> 1)) + (zq & 1) * 4) = z;
  }

  // per-thread x-staging geometry (3 coalesced float4 per thread per element)
  const int f0 = tid * 4, f1 = f0 + 1024, f2 = f0 + 2048;
  const int xw0 = sw(f0 / 48, f0 % 48);
  const int xw1 = sw(f1 / 48, f1 % 48);
  const int xw2 = sw(f2 / 48, f2 % 48);
  const int zr = tid >> 2, zq = tid & 3;
  const int zpad = swc(zr, 6 + (zq >> 1)) + (zq & 1) * 4;

  // A-fragment addresses (own 16-row tile)
  const int ar = 16 * w + col;
  const int a0 = swc(ar, qd), a1 = swc(ar, qd + 4);

  // ---- prefetch x_0 ----
  const float* xb = x + b0 * 3072;
  float4 p0 = *(const float4*)(xb + f0);
  float4 p1 = *(const float4*)(xb + f1);
  float4 p2 = *(const float4*)(xb + f2);

  for (int i = 0; i < NB; ++i) {
    if (i > 0) __syncthreads();  // B_top: PV_{i-1} reads of X(P) and VT done

    // ---- write staged x_i regs -> X; re-zero K-pad (P_{i-1} clobbered it) ----
    {
      ushort4 s;
      s.x = f2b(p0.x); s.y = f2b(p0.y); s.z = f2b(p0.z); s.w = f2b(p0.w);
      *(ushort4*)(X + xw0) = s;
      s.x = f2b(p1.x); s.y = f2b(p1.y); s.z = f2b(p1.z); s.w = f2b(p1.w);
      *(ushort4*)(X + xw1) = s;
      s.x = f2b(p2.x); s.y = f2b(p2.y); s.z = f2b(p2.z); s.w = f2b(p2.w);
      *(ushort4*)(X + xw2) = s;
      ushort4 z = {0, 0, 0, 0};
      *(ushort4*)(X + zpad) = z;
    }
    // ---- issue prefetch for x_{i+1} (clamped; overlaps all compute below) ----
    {
      const long bn = b0 + ((i < NB - 1) ? i + 1 : i);
      const float* xn = x + bn * 3072;
      p0 = *(const float4*)(xn + f0);
      p1 = *(const float4*)(xn + f1);
      p2 = *(const float4*)(xn + f2);
    }
    __syncthreads();  // B_stage: X_i (and W on i=0) visible to all waves

    // ---- projections: V = x@Wv -> VT (transposed), QM = x@M -> regs ----
    f32x4 aq[3];
    {
      const bf16x8 xa0 = *(const bf16x8*)(X + a0);
      const bf16x8 xa1 = *(const bf16x8*)(X + a1);
      const u16* WM = W;
      const u16* WV = W + 48 * 64;
#pragma unroll
      for (int n = 0; n < 3; ++n) {
        const int br = 16 * n + col;
        const int c0 = swc(br, qd), c1 = swc(br, qd + 4);
        f32x4 av = {0.f, 0.f, 0.f, 0.f};
        av = mfma16(xa0, *(const bf16x8*)(WV + c0), av);
        av = mfma16(xa1, *(const bf16x8*)(WV + c1), av);
        f32x4 a = {0.f, 0.f, 0.f, 0.f};
        a = mfma16(xa0, *(const bf16x8*)(WM + c0), a);
        a = mfma16(xa1, *(const bf16x8*)(WM + c1), a);
        aq[n] = a;
        ushort4 pv;  // D[s_loc][h_loc] -> VT[h][s], 4 consecutive s
        pv.x = f2b(av[0]); pv.y = f2b(av[1]); pv.z = f2b(av[2]); pv.w = f2b(av[3]);
        *(ushort4*)(VT + sw(16 * n + col, 16 * w + qd * 4)) = pv;
      }
    }

    // ---- QM write: per-wave-private rows -> fence suffices, no barrier ----
#pragma unroll
    for (int n = 0; n < 3; ++n)
#pragma unroll
      for (int j = 0; j < 4; ++j)
        QM[sw(16 * w + qd * 4 + j, 16 * n + col)] = f2b(aq[n][j]);
    __threadfence_block();

    // ---- S = QM @ X^T ----
    float sv[4][4];
    {
      const bf16x8 qa0 = *(const bf16x8*)(QM + a0);
      const bf16x8 qa1 = *(const bf16x8*)(QM + a1);
#pragma unroll
      for (int st = 0; st < 4; ++st) {
        const int br = 16 * st + col;
        f32x4 a = {0.f, 0.f, 0.f, 0.f};
        a = mfma16(qa0, *(const bf16x8*)(X + swc(br, qd)), a);
        a = mfma16(qa1, *(const bf16x8*)(X + swc(br, qd + 4)), a);
#pragma unroll
        for (int j = 0; j < 4; ++j) sv[st][j] = a[j];
      }
    }

    // ---- causal mask + softmax (16-lane butterflies) ----
    float m4[4] = {-INFINITY, -INFINITY, -INFINITY, -INFINITY};
#pragma unroll
    for (int st = 0; st < 4; ++st)
#pragma unroll
      for (int j = 0; j < 4; ++j) {
        int tg = 16 * w + qd * 4 + j;
        int sg = 16 * st + col;
        float v = (sg <= tg) ? sv[st][j] : -INFINITY;
        sv[st][j] = v;
        m4[j] = fmaxf(m4[j], v);
      }
#pragma unroll
    for (int d = 1; d < 16; d <<= 1)
#pragma unroll
      for (int j = 0; j < 4; ++j) m4[j] = fmaxf(m4[j], __shfl_xor(m4[j], d, 64));
    float l4[4] = {0.f, 0.f, 0.f, 0.f};
#pragma unroll
    for (int st = 0; st < 4; ++st)
#pragma unroll
      for (int j = 0; j < 4; ++j) {
        float p = __expf(sv[st][j] - m4[j]);  // exp(-inf)=0 handles the mask
        sv[st][j] = p;
        l4[j] += p;
      }
#pragma unroll
    for (int d = 1; d < 16; d <<= 1)
#pragma unroll
      for (int j = 0; j < 4; ++j) l4[j] += __shfl_xor(l4[j], d, 64);

    __syncthreads();  // B_mid: all S reads of X done; VT writes complete

    // ---- write P' (unnormalized) over X: own rows -> fence suffices ----
#pragma unroll
    for (int st = 0; st < 4; ++st)
#pragma unroll
      for (int j = 0; j < 4; ++j)
        X[sw(16 * w + qd * 4 + j, 16 * st + col)] = f2b(sv[st][j]);
    __threadfence_block();

    // ---- O = P' @ V; scale rows by 1/l ----
    f32x4 o0 = {0.f, 0.f, 0.f, 0.f}, o1 = o0, o2 = o0;
    {
      const int pr = 16 * w + col;
#pragma unroll
      for (int kt = 0; kt < 2; ++kt) {
        const int ch = qd + 4 * kt;
        bf16x8 pa = *(const bf16x8*)(X + swc(pr, ch));
        o0 = mfma16(pa, *(const bf16x8*)(VT + swc(0  + col, ch)), o0);
        o1 = mfma16(pa, *(const bf16x8*)(VT + swc(16 + col, ch)), o1);
        o2 = mfma16(pa, *(const bf16x8*)(VT + swc(32 + col, ch)), o2);
      }
    }
    float rl[4];
#pragma unroll
    for (int j = 0; j < 4; ++j) rl[j] = __builtin_amdgcn_rcpf(l4[j]);

    float* ob = out + (b0 + i) * 3072 + (16 * w + qd * 4) * 48 + col;
#pragma unroll
    for (int j = 0; j < 4; ++j) {  // per-quad 64B segments -> fine coalescing
      ob[j * 48 +  0] = o0[j] * rl[j];
      ob[j * 48 + 16] = o1[j] * rl[j];
      ob[j * 48 + 32] = o2[j] * rl[j];
    }
  }
}

extern "C" void kernel_launch(void* const* d_in, const int* in_sizes, int n_in,
                              void* d_out, int out_size, void* d_ws, size_t ws_size,
                              hipStream_t stream) {
  const float* x  = (const float*)d_in[0];
  const float* Wq = (const float*)d_in[1];
  const float* Wk = (const float*)d_in[2];
  const float* Wv = (const float*)d_in[3];
  u16* wimg = (u16*)d_ws;  // 96*64 u16 = 12288 B
  head_prep<<<1, 256, 0, stream>>>(Wq, Wk, Wv, wimg);
  head_main<<<16384 / NB, 256, 0, stream>>>(x, wimg, (float*)d_out);
}